// Round 1
// baseline (1813.862 us; speedup 1.0000x reference)
//
#include <hip/hip_runtime.h>
#include <cmath>

#define HC 64   // H*C
#define NH 4    // heads
#define CC 16   // channels per head

__device__ __forceinline__ unsigned encodeOrd(float f) {
    unsigned u = __float_as_uint(f);
    return (u & 0x80000000u) ? ~u : (u | 0x80000000u);
}
__device__ __forceinline__ float decodeOrd(unsigned u) {
    return (u & 0x80000000u) ? __uint_as_float(u ^ 0x80000000u)
                             : __uint_as_float(~u);
}

// xl = x@Wl + bl ; xr = x@Wr + br   (one block per node, 64 threads)
__global__ void lin_nodes_k(const float* __restrict__ x, int din,
                            const float* __restrict__ Wl, const float* __restrict__ bl,
                            const float* __restrict__ Wr, const float* __restrict__ br,
                            float* __restrict__ xl, float* __restrict__ xr) {
    int node = blockIdx.x;
    int c = threadIdx.x;
    extern __shared__ float sx[];
    for (int i = c; i < din; i += HC) sx[i] = x[(size_t)node * din + i];
    __syncthreads();
    float accl = bl[c], accr = br[c];
    for (int k = 0; k < din; ++k) {
        float xv = sx[k];
        accl = fmaf(xv, Wl[k * HC + c], accl);
        accr = fmaf(xv, Wr[k * HC + c], accr);
    }
    xl[(size_t)node * HC + c] = accl;
    xr[(size_t)node * HC + c] = accr;
}

// wave per edge: logits a[e][h] and atomicMax into amax[dst][h]
__global__ void edge_logits_k(const float* __restrict__ xl, const float* __restrict__ xr,
                              const float* __restrict__ eattr, const float* __restrict__ We,
                              const float* __restrict__ att,
                              const int* __restrict__ src, const int* __restrict__ dst,
                              float* __restrict__ elog, unsigned* __restrict__ amax, int E) {
    int t = blockIdx.x * blockDim.x + threadIdx.x;
    int e = t >> 6;
    int c = t & 63;
    if (e >= E) return;
    int s = src[e], d = dst[e];
    float ev = 0.f;
#pragma unroll
    for (int k = 0; k < 4; ++k) ev = fmaf(eattr[e * 4 + k], We[k * HC + c], ev);
    float m = xl[(size_t)s * HC + c] + xr[(size_t)d * HC + c] + ev;
    m = m > 0.f ? m : 0.2f * m;           // LeakyReLU(0.2)
    float v = m * att[c];                 // att[h*16+cc], c == h*16+cc
    v += __shfl_xor(v, 1);
    v += __shfl_xor(v, 2);
    v += __shfl_xor(v, 4);
    v += __shfl_xor(v, 8);
    if ((c & 15) == 0) {
        int h = c >> 4;
        elog[(size_t)e * NH + h] = v;
        atomicMax(&amax[d * NH + h], encodeOrd(v));
    }
}

// thread per (edge, head): p = exp(a - amax[dst]); asum[dst] += p
__global__ void edge_exp_k(float* __restrict__ elog, const unsigned* __restrict__ amax,
                           float* __restrict__ asum, const int* __restrict__ dst, int E) {
    int t = blockIdx.x * blockDim.x + threadIdx.x;
    if (t >= E * NH) return;
    int e = t >> 2;
    int h = t & 3;
    int d = dst[e];
    float a = elog[t];
    float p = expf(a - decodeOrd(amax[d * NH + h]));
    elog[t] = p;
    atomicAdd(&asum[d * NH + h], p);
}

// wave per edge: out[dst][c] += xl[src][c] * alpha[e][h]
__global__ void edge_accum_k(const float* __restrict__ elog, const float* __restrict__ asum,
                             const float* __restrict__ xl,
                             const int* __restrict__ src, const int* __restrict__ dst,
                             float* __restrict__ out, int E) {
    int t = blockIdx.x * blockDim.x + threadIdx.x;
    int e = t >> 6;
    int c = t & 63;
    if (e >= E) return;
    int s = src[e], d = dst[e];
    int h = c >> 4;
    float p = elog[(size_t)e * NH + h];
    float alpha = p / (asum[d * NH + h] + 1e-16f);
    atomicAdd(&out[(size_t)d * HC + c], xl[(size_t)s * HC + c] * alpha);
}

// per-channel sum / sumsq (grid-strided rows, atomic partials)
__global__ void bn_stats_k(const float* __restrict__ x, float* __restrict__ sums,
                           float* __restrict__ sqs, int n) {
    int c = threadIdx.x;  // 0..63
    int rows_per = (n + gridDim.x - 1) / gridDim.x;
    int r0 = blockIdx.x * rows_per;
    int r1 = min(n, r0 + rows_per);
    float s = 0.f, q = 0.f;
    for (int r = r0; r < r1; ++r) {
        float v = x[(size_t)r * HC + c];
        s += v;
        q = fmaf(v, v, q);
    }
    atomicAdd(&sums[c], s);
    atomicAdd(&sqs[c], q);
}

// x = elu((x - mu) * rsqrt(var+eps) * g + be)   in place
__global__ void bn_apply_elu_k(float* __restrict__ x, const float* __restrict__ sums,
                               const float* __restrict__ sqs, const float* __restrict__ g,
                               const float* __restrict__ be, int n) {
    int idx = blockIdx.x * blockDim.x + threadIdx.x;
    if (idx >= n * HC) return;
    int c = idx & 63;
    float inv_n = 1.0f / n;
    float mu = sums[c] * inv_n;
    float var = sqs[c] * inv_n - mu * mu;
    float v = (x[idx] - mu) * rsqrtf(var + 1e-5f) * g[c] + be[c];
    x[idx] = v > 0.f ? v : expf(v) - 1.0f;
}

// y = x @ W + b  (64 -> 64), block per node
__global__ void fc64_k(const float* __restrict__ x, const float* __restrict__ W,
                       const float* __restrict__ b, float* __restrict__ y) {
    int node = blockIdx.x;
    int c = threadIdx.x;
    __shared__ float sx[HC];
    sx[c] = x[(size_t)node * HC + c];
    __syncthreads();
    float acc = b[c];
    for (int k = 0; k < HC; ++k) acc = fmaf(sx[k], W[k * HC + c], acc);
    y[(size_t)node * HC + c] = acc;
}

// out[n] = 5*tanh(dot(z[n], W2) + b2)  (wave per node)
__global__ void final_k(const float* __restrict__ z, const float* __restrict__ W2,
                        const float* __restrict__ b2, float* __restrict__ out, int n) {
    int t = blockIdx.x * blockDim.x + threadIdx.x;
    int node = t >> 6;
    int c = t & 63;
    if (node >= n) return;
    float v = z[(size_t)node * HC + c] * W2[c];
    v += __shfl_xor(v, 1);
    v += __shfl_xor(v, 2);
    v += __shfl_xor(v, 4);
    v += __shfl_xor(v, 8);
    v += __shfl_xor(v, 16);
    v += __shfl_xor(v, 32);
    if (c == 0) out[node] = 5.0f * tanhf(v + b2[0]);
}

extern "C" void kernel_launch(void* const* d_in, const int* in_sizes, int n_in,
                              void* d_out, int out_size, void* d_ws, size_t ws_size,
                              hipStream_t stream) {
    const float* x0    = (const float*)d_in[0];
    const int*   eidx  = (const int*)d_in[1];
    const float* eattr = (const float*)d_in[2];

    // per-layer params: Wl, bl, Wr, br, We, att, bias, g, be  (9 each)
    const float* Wl[2]; const float* bl[2]; const float* Wr[2]; const float* br[2];
    const float* We[2]; const float* att[2]; const float* g[2]; const float* be[2];
    for (int l = 0; l < 2; ++l) {
        int base = 3 + l * 9;
        Wl[l]  = (const float*)d_in[base + 0];
        bl[l]  = (const float*)d_in[base + 1];
        Wr[l]  = (const float*)d_in[base + 2];
        br[l]  = (const float*)d_in[base + 3];
        We[l]  = (const float*)d_in[base + 4];
        att[l] = (const float*)d_in[base + 5];
        // base+6 = bias (cancels under BN), base+7 = g, base+8 = be
        g[l]   = (const float*)d_in[base + 7];
        be[l]  = (const float*)d_in[base + 8];
    }
    const float* W1 = (const float*)d_in[21];
    const float* b1 = (const float*)d_in[22];
    const float* gf = (const float*)d_in[23];
    const float* bf = (const float*)d_in[24];
    const float* W2 = (const float*)d_in[25];
    const float* b2 = (const float*)d_in[26];

    const int N = in_sizes[0] / 128;
    const int E = in_sizes[1] / 2;
    const int* src = eidx;
    const int* dst = eidx + E;

    // workspace layout (all 4-byte elements)
    float* ws = (float*)d_ws;
    size_t o = 0;
    float*    xl   = ws + o; o += (size_t)N * HC;
    float*    xr   = ws + o; o += (size_t)N * HC;
    float*    elog = ws + o; o += (size_t)E * NH;
    unsigned* amax = (unsigned*)(ws + o); o += (size_t)N * NH;
    float*    asum = ws + o; o += (size_t)N * NH;
    float*    buf1 = ws + o; o += (size_t)N * HC;
    float*    buf2 = ws + o; o += (size_t)N * HC;
    float*    sums = ws + o; o += HC;
    float*    sqs  = ws + o; o += HC;

    const int edge_waves_blocks = (int)(((size_t)E * 64 + 255) / 256);
    const int edge_eh_blocks    = (int)(((size_t)E * NH + 255) / 256);
    const int node_elem_blocks  = (int)(((size_t)N * HC + 255) / 256);

    const float* x_cur = x0;
    int din = 128;
    float* acc_buf[2] = {buf1, buf2};

    for (int l = 0; l < 2; ++l) {
        float* hout = acc_buf[l];
        hipMemsetAsync(amax, 0, (size_t)N * NH * 4, stream);
        hipMemsetAsync(asum, 0, (size_t)N * NH * 4, stream);
        hipMemsetAsync(hout, 0, (size_t)N * HC * 4, stream);
        hipMemsetAsync(sums, 0, HC * 4, stream);
        hipMemsetAsync(sqs, 0, HC * 4, stream);

        lin_nodes_k<<<N, HC, din * 4, stream>>>(x_cur, din, Wl[l], bl[l], Wr[l], br[l], xl, xr);
        edge_logits_k<<<edge_waves_blocks, 256, 0, stream>>>(xl, xr, eattr, We[l], att[l],
                                                             src, dst, elog, amax, E);
        edge_exp_k<<<edge_eh_blocks, 256, 0, stream>>>(elog, amax, asum, dst, E);
        edge_accum_k<<<edge_waves_blocks, 256, 0, stream>>>(elog, asum, xl, src, dst, hout, E);
        bn_stats_k<<<256, HC, 0, stream>>>(hout, sums, sqs, N);
        bn_apply_elu_k<<<node_elem_blocks, 256, 0, stream>>>(hout, sums, sqs, g[l], be[l], N);

        x_cur = hout;
        din = HC;
    }

    // head: fc1 (64->64) -> BN -> ELU -> fc2 (64->1) -> 5*tanh
    float* y = buf1;  // buf2 holds layer-1 output (x_cur)
    fc64_k<<<N, HC, 0, stream>>>(x_cur, W1, b1, y);
    hipMemsetAsync(sums, 0, HC * 4, stream);
    hipMemsetAsync(sqs, 0, HC * 4, stream);
    bn_stats_k<<<256, HC, 0, stream>>>(y, sums, sqs, N);
    bn_apply_elu_k<<<node_elem_blocks, 256, 0, stream>>>(y, sums, sqs, gf, bf, N);
    final_k<<<(int)(((size_t)N * 64 + 255) / 256), 256, 0, stream>>>(y, W2, b2, (float*)d_out, N);
}

// Round 2
// 1056.876 us; speedup vs baseline: 1.7162x; 1.7162x over previous
//
#include <hip/hip_runtime.h>
#include <cmath>

#define HC 64   // H*C
#define NH 4    // heads

// ---------------- CSR build ----------------

__global__ void hist_k(const int* __restrict__ dst, int* __restrict__ deg, int E) {
    int e = blockIdx.x * blockDim.x + threadIdx.x;
    if (e < E) atomicAdd(&deg[dst[e]], 1);
}

// single-block exclusive scan over n entries (n ~ 50000), row_start[n] = total
__global__ void scan_k(const int* __restrict__ deg, int* __restrict__ row_start, int n) {
    __shared__ int carry;
    __shared__ int tmp[1024];
    int t = threadIdx.x;
    if (t == 0) carry = 0;
    __syncthreads();
    for (int base = 0; base < n; base += 1024) {
        int i = base + t;
        int v = (i < n) ? deg[i] : 0;
        tmp[t] = v;
        __syncthreads();
        for (int off = 1; off < 1024; off <<= 1) {
            int add = (t >= off) ? tmp[t - off] : 0;
            __syncthreads();
            tmp[t] += add;
            __syncthreads();
        }
        if (i < n) row_start[i] = carry + tmp[t] - v;  // exclusive
        __syncthreads();
        if (t == 0) carry += tmp[1023];
        __syncthreads();
    }
    if (t == 0) row_start[n] = carry;
}

__global__ void scatter_k(const int* __restrict__ src, const int* __restrict__ dst,
                          const float* __restrict__ eattr,
                          const int* __restrict__ row_start, int* __restrict__ cursor,
                          int* __restrict__ src_sorted, float4* __restrict__ eattr_sorted,
                          int E) {
    int e = blockIdx.x * blockDim.x + threadIdx.x;
    if (e >= E) return;
    int d = dst[e];
    int pos = row_start[d] + atomicAdd(&cursor[d], 1);
    src_sorted[pos] = src[e];
    eattr_sorted[pos] = ((const float4*)eattr)[e];
}

// ---------------- node linear (xl, xr), W staged in LDS, 4 nodes/block ----------------

__global__ void lin2_k(const float* __restrict__ x, int din, int n,
                       const float* __restrict__ Wl, const float* __restrict__ bl,
                       const float* __restrict__ Wr, const float* __restrict__ br,
                       float* __restrict__ xl, float* __restrict__ xr) {
    __shared__ float sWl[64 * 64];
    __shared__ float sWr[64 * 64];
    int t = threadIdx.x;
    int c = t & 63;
    int node = blockIdx.x * 4 + (t >> 6);
    float accl = bl[c], accr = br[c];
    const float* xrow = x + (size_t)node * din;
    for (int k0 = 0; k0 < din; k0 += 64) {
        __syncthreads();
        for (int i = t; i < 64 * 64; i += 256) {
            sWl[i] = Wl[(size_t)(k0 + (i >> 6)) * HC + (i & 63)];
            sWr[i] = Wr[(size_t)(k0 + (i >> 6)) * HC + (i & 63)];
        }
        __syncthreads();
        if (node < n) {
            for (int k = 0; k < 64; ++k) {
                float xv = xrow[k0 + k];
                accl = fmaf(xv, sWl[k * 64 + c], accl);
                accr = fmaf(xv, sWr[k * 64 + c], accr);
            }
        }
    }
    if (node < n) {
        xl[(size_t)node * HC + c] = accl;
        xr[(size_t)node * HC + c] = accr;
    }
}

// ---------------- fused GAT: wave per destination node, online softmax ----------------

__global__ void gat_node_k(const float* __restrict__ xl, const float* __restrict__ xr,
                           const float* __restrict__ We, const float* __restrict__ att,
                           const int* __restrict__ row_start, const int* __restrict__ src_sorted,
                           const float4* __restrict__ eattr_sorted,
                           float* __restrict__ out, int n) {
    __shared__ float sWe[4 * 64];
    __shared__ float satt[64];
    int t = threadIdx.x;
    if (t < 256) sWe[t] = We[t];
    if (t < 64) satt[t] = att[t];
    __syncthreads();
    int c = t & 63;
    int node = blockIdx.x * 4 + (t >> 6);
    if (node >= n) return;

    float xrd = xr[(size_t)node * HC + c];
    int rs = row_start[node], re = row_start[node + 1];
    float mrun = -INFINITY, srun = 0.f, acc = 0.f;
    for (int i = rs; i < re; ++i) {
        int s = src_sorted[i];
        float4 ea = eattr_sorted[i];
        float ev = ea.x * sWe[c] + ea.y * sWe[64 + c] + ea.z * sWe[128 + c] + ea.w * sWe[192 + c];
        float xls = xl[(size_t)s * HC + c];
        float mm = xls + xrd + ev;
        mm = mm > 0.f ? mm : 0.2f * mm;       // LeakyReLU(0.2)
        float v = mm * satt[c];
        v += __shfl_xor(v, 1);
        v += __shfl_xor(v, 2);
        v += __shfl_xor(v, 4);
        v += __shfl_xor(v, 8);                // head logit, all 16 lanes of head
        float newm = fmaxf(mrun, v);
        float sc = __expf(mrun - newm);
        float p  = __expf(v - newm);
        srun = fmaf(srun, sc, p);
        acc  = fmaf(acc, sc, p * xls);
        mrun = newm;
    }
    out[(size_t)node * HC + c] = acc / (srun + 1e-16f);
}

// ---------------- BN stats / apply ----------------

__global__ void bn_stats_k(const float* __restrict__ x, float* __restrict__ sums,
                           float* __restrict__ sqs, int n) {
    int c = threadIdx.x;  // 0..63
    int rows_per = (n + gridDim.x - 1) / gridDim.x;
    int r0 = blockIdx.x * rows_per;
    int r1 = min(n, r0 + rows_per);
    float s = 0.f, q = 0.f;
    for (int r = r0; r < r1; ++r) {
        float v = x[(size_t)r * HC + c];
        s += v;
        q = fmaf(v, v, q);
    }
    atomicAdd(&sums[c], s);
    atomicAdd(&sqs[c], q);
}

__global__ void bn_apply_elu_k(float* __restrict__ x, const float* __restrict__ sums,
                               const float* __restrict__ sqs, const float* __restrict__ g,
                               const float* __restrict__ be, int n) {
    int idx = blockIdx.x * blockDim.x + threadIdx.x;
    if (idx >= n * HC) return;
    int c = idx & 63;
    float inv_n = 1.0f / n;
    float mu = sums[c] * inv_n;
    float var = sqs[c] * inv_n - mu * mu;
    float v = (x[idx] - mu) * rsqrtf(var + 1e-5f) * g[c] + be[c];
    x[idx] = v > 0.f ? v : expf(v) - 1.0f;
}

// ---------------- head: fc 64->64 (W in LDS, 4 nodes/block), final dot ----------------

__global__ void lin1_k(const float* __restrict__ x, const float* __restrict__ W,
                       const float* __restrict__ b, float* __restrict__ y, int n) {
    __shared__ float sW[64 * 64];
    int t = threadIdx.x;
    int c = t & 63;
    int node = blockIdx.x * 4 + (t >> 6);
    for (int i = t; i < 64 * 64; i += 256) sW[i] = W[i];
    __syncthreads();
    if (node >= n) return;
    const float* xrow = x + (size_t)node * HC;
    float acc = b[c];
    for (int k = 0; k < 64; ++k) acc = fmaf(xrow[k], sW[k * 64 + c], acc);
    y[(size_t)node * HC + c] = acc;
}

__global__ void final_k(const float* __restrict__ z, const float* __restrict__ W2,
                        const float* __restrict__ b2, float* __restrict__ out, int n) {
    int t = blockIdx.x * blockDim.x + threadIdx.x;
    int node = t >> 6;
    int c = t & 63;
    if (node >= n) return;
    float v = z[(size_t)node * HC + c] * W2[c];
    v += __shfl_xor(v, 1);
    v += __shfl_xor(v, 2);
    v += __shfl_xor(v, 4);
    v += __shfl_xor(v, 8);
    v += __shfl_xor(v, 16);
    v += __shfl_xor(v, 32);
    if (c == 0) out[node] = 5.0f * tanhf(v + b2[0]);
}

// ---------------- launch ----------------

extern "C" void kernel_launch(void* const* d_in, const int* in_sizes, int n_in,
                              void* d_out, int out_size, void* d_ws, size_t ws_size,
                              hipStream_t stream) {
    const float* x0    = (const float*)d_in[0];
    const int*   eidx  = (const int*)d_in[1];
    const float* eattr = (const float*)d_in[2];

    const float* Wl[2]; const float* bl[2]; const float* Wr[2]; const float* br[2];
    const float* We[2]; const float* att[2]; const float* g[2]; const float* be[2];
    for (int l = 0; l < 2; ++l) {
        int base = 3 + l * 9;
        Wl[l]  = (const float*)d_in[base + 0];
        bl[l]  = (const float*)d_in[base + 1];
        Wr[l]  = (const float*)d_in[base + 2];
        br[l]  = (const float*)d_in[base + 3];
        We[l]  = (const float*)d_in[base + 4];
        att[l] = (const float*)d_in[base + 5];
        // base+6 = bias: constant per channel, cancels exactly under BatchNorm
        g[l]   = (const float*)d_in[base + 7];
        be[l]  = (const float*)d_in[base + 8];
    }
    const float* W1 = (const float*)d_in[21];
    const float* b1 = (const float*)d_in[22];
    const float* gf = (const float*)d_in[23];
    const float* bf = (const float*)d_in[24];
    const float* W2 = (const float*)d_in[25];
    const float* b2 = (const float*)d_in[26];

    const int N = in_sizes[0] / 128;
    const int E = in_sizes[1] / 2;
    const int* src = eidx;
    const int* dst = eidx + E;

    // workspace layout (floats); eattr_sorted first for float4 alignment
    float* ws = (float*)d_ws;
    size_t o = 0;
    float4* eattr_sorted = (float4*)(ws + o); o += (size_t)E * 4;
    float*  xl   = ws + o; o += (size_t)N * HC;
    float*  xr   = ws + o; o += (size_t)N * HC;
    float*  buf1 = ws + o; o += (size_t)N * HC;
    float*  buf2 = ws + o; o += (size_t)N * HC;
    int*    src_sorted = (int*)(ws + o); o += (size_t)E;
    int*    row_start  = (int*)(ws + o); o += (size_t)N + 2;
    int*    deg        = (int*)(ws + o); o += (size_t)N;
    int*    cursor     = (int*)(ws + o); o += (size_t)N;
    float*  sums = ws + o; o += HC;
    float*  sqs  = ws + o; o += HC;

    const int node4_blocks     = (N + 3) / 4;
    const int edge_blocks      = (E + 255) / 256;
    const int node_elem_blocks = (int)(((size_t)N * HC + 255) / 256);

    // ---- CSR build (once, shared by both layers) ----
    hipMemsetAsync(deg, 0, (size_t)N * 4, stream);
    hipMemsetAsync(cursor, 0, (size_t)N * 4, stream);
    hist_k<<<edge_blocks, 256, 0, stream>>>(dst, deg, E);
    scan_k<<<1, 1024, 0, stream>>>(deg, row_start, N);
    scatter_k<<<edge_blocks, 256, 0, stream>>>(src, dst, eattr, row_start, cursor,
                                               src_sorted, eattr_sorted, E);

    const float* x_cur = x0;
    int din = 128;
    float* acc_buf[2] = {buf1, buf2};

    for (int l = 0; l < 2; ++l) {
        float* hout = acc_buf[l];
        lin2_k<<<node4_blocks, 256, 0, stream>>>(x_cur, din, N, Wl[l], bl[l], Wr[l], br[l], xl, xr);
        gat_node_k<<<node4_blocks, 256, 0, stream>>>(xl, xr, We[l], att[l], row_start,
                                                     src_sorted, eattr_sorted, hout, N);
        hipMemsetAsync(sums, 0, HC * 4, stream);
        hipMemsetAsync(sqs, 0, HC * 4, stream);
        bn_stats_k<<<256, HC, 0, stream>>>(hout, sums, sqs, N);
        bn_apply_elu_k<<<node_elem_blocks, 256, 0, stream>>>(hout, sums, sqs, g[l], be[l], N);
        x_cur = hout;
        din = HC;
    }

    // head: fc1 (64->64) -> BN -> ELU -> fc2 (64->1) -> 5*tanh
    float* y = buf1;  // buf2 holds layer-1 output (x_cur)
    lin1_k<<<node4_blocks, 256, 0, stream>>>(x_cur, W1, b1, y, N);
    hipMemsetAsync(sums, 0, HC * 4, stream);
    hipMemsetAsync(sqs, 0, HC * 4, stream);
    bn_stats_k<<<256, HC, 0, stream>>>(y, sums, sqs, N);
    bn_apply_elu_k<<<node_elem_blocks, 256, 0, stream>>>(y, sums, sqs, gf, bf, N);
    final_k<<<(int)(((size_t)N * 64 + 255) / 256), 256, 0, stream>>>(y, W2, b2, (float*)d_out, N);
}

// Round 3
// 649.794 us; speedup vs baseline: 2.7914x; 1.6265x over previous
//
#include <hip/hip_runtime.h>
#include <hip/hip_bf16.h>
#include <cmath>

#define HC 64
typedef __hip_bfloat16 bf16;

// ---------------- CSR build ----------------

__global__ void hist_k(const int* __restrict__ dst, int* __restrict__ deg, int E) {
    int e = blockIdx.x * blockDim.x + threadIdx.x;
    if (e < E) atomicAdd(&deg[dst[e]], 1);
}

// phase 1: per-256-chunk exclusive scan + chunk totals
__global__ void scan1_k(const int* __restrict__ deg, int* __restrict__ row_start,
                        int* __restrict__ btot, int n) {
    __shared__ int tmp[256];
    int t = threadIdx.x;
    int i = blockIdx.x * 256 + t;
    int v = (i < n) ? deg[i] : 0;
    tmp[t] = v;
    __syncthreads();
    for (int off = 1; off < 256; off <<= 1) {
        int a = (t >= off) ? tmp[t - off] : 0;
        __syncthreads();
        tmp[t] += a;
        __syncthreads();
    }
    if (i < n) row_start[i] = tmp[t] - v;      // block-local exclusive
    if (t == 255) btot[blockIdx.x] = tmp[255];
}

// phase 2: exclusive scan of block totals (nb <= 256); writes grand total
__global__ void scan2_k(int* __restrict__ btot, int nb, int* __restrict__ row_start, int n) {
    __shared__ int tmp[256];
    int t = threadIdx.x;
    int v = (t < nb) ? btot[t] : 0;
    tmp[t] = v;
    __syncthreads();
    for (int off = 1; off < 256; off <<= 1) {
        int a = (t >= off) ? tmp[t - off] : 0;
        __syncthreads();
        tmp[t] += a;
        __syncthreads();
    }
    if (t < nb) btot[t] = tmp[t] - v;          // exclusive block offsets
    if (t == 255) row_start[n] = tmp[255];     // grand total
}

// phase 3: add block offsets
__global__ void scan3_k(int* __restrict__ row_start, const int* __restrict__ btot, int n) {
    int i = blockIdx.x * blockDim.x + threadIdx.x;
    if (i < n) row_start[i] += btot[i >> 8];
}

__global__ void scatter_k(const int* __restrict__ src, const int* __restrict__ dst,
                          const float* __restrict__ eattr,
                          const int* __restrict__ row_start, int* __restrict__ cursor,
                          int* __restrict__ src_sorted, float4* __restrict__ eattr_sorted,
                          int E) {
    int e = blockIdx.x * blockDim.x + threadIdx.x;
    if (e >= E) return;
    int d = dst[e];
    int pos = row_start[d] + atomicAdd(&cursor[d], 1);
    src_sorted[pos] = src[e];
    eattr_sorted[pos] = ((const float4*)eattr)[e];
}

// ---------------- layer-0 linear: din=128, raw input, full W in LDS ----------------

__global__ void lin128_k(const float* __restrict__ x, int n,
                         const float* __restrict__ Wl, const float* __restrict__ bl,
                         const float* __restrict__ Wr, const float* __restrict__ br,
                         bf16* __restrict__ xl, float* __restrict__ xr, int ngroups) {
    __shared__ float sWl[128 * 64];
    __shared__ float sWr[128 * 64];
    __shared__ float sx[4 * 128];
    int t = threadIdx.x;
    for (int i = t; i < 128 * 64; i += 256) { sWl[i] = Wl[i]; sWr[i] = Wr[i]; }
    int c = t & 63, nd = t >> 6;
    float blc = bl[c], brc = br[c];
    for (int gs = blockIdx.x; gs < ngroups; gs += gridDim.x) {
        int node0 = gs * 4;
        __syncthreads();
        for (int i = t; i < 4 * 128; i += 256) {
            int r = node0 + (i >> 7);
            sx[i] = (r < n) ? x[(size_t)r * 128 + (i & 127)] : 0.f;
        }
        __syncthreads();
        float accl = blc, accr = brc;
        const float* sxr = sx + nd * 128;
#pragma unroll 8
        for (int k = 0; k < 128; ++k) {
            float xv = sxr[k];
            accl = fmaf(xv, sWl[k * 64 + c], accl);
            accr = fmaf(xv, sWr[k * 64 + c], accr);
        }
        int node = node0 + nd;
        if (node < n) {
            xl[(size_t)node * 64 + c] = __float2bfloat16(accl);
            xr[(size_t)node * 64 + c] = accr;
        }
    }
}

// ---------------- layer-1 linear: din=64, fused input BN+ELU ----------------

__global__ void lin64bn_k(const float* __restrict__ x, int n,
                          const float* __restrict__ sums, const float* __restrict__ sqs,
                          const float* __restrict__ g, const float* __restrict__ be,
                          const float* __restrict__ Wl, const float* __restrict__ bl,
                          const float* __restrict__ Wr, const float* __restrict__ br,
                          bf16* __restrict__ xl, float* __restrict__ xr, int ngroups) {
    __shared__ float sWl[64 * 64];
    __shared__ float sWr[64 * 64];
    __shared__ float sx[4 * 64];
    int t = threadIdx.x;
    for (int i = t; i < 64 * 64; i += 256) { sWl[i] = Wl[i]; sWr[i] = Wr[i]; }
    int c = t & 63, nd = t >> 6;
    float inv_n = 1.f / n;
    float mu = sums[c] * inv_n;
    float var = sqs[c] * inv_n - mu * mu;
    float scc = rsqrtf(var + 1e-5f) * g[c];
    float sh = be[c] - mu * scc;
    float blc = bl[c], brc = br[c];
    for (int gs = blockIdx.x; gs < ngroups; gs += gridDim.x) {
        int node0 = gs * 4;
        __syncthreads();
        {
            int r = node0 + nd;
            float v = (r < n) ? x[(size_t)r * 64 + c] : 0.f;
            v = v * scc + sh;
            sx[t] = v > 0.f ? v : __expf(v) - 1.f;   // ELU
        }
        __syncthreads();
        float accl = blc, accr = brc;
        const float* sxr = sx + nd * 64;
#pragma unroll 8
        for (int k = 0; k < 64; ++k) {
            float xv = sxr[k];
            accl = fmaf(xv, sWl[k * 64 + c], accl);
            accr = fmaf(xv, sWr[k * 64 + c], accr);
        }
        int node = node0 + nd;
        if (node < n) {
            xl[(size_t)node * 64 + c] = __float2bfloat16(accl);
            xr[(size_t)node * 64 + c] = accr;
        }
    }
}

// ---------------- fused GAT: wave per destination node, direct-exp softmax ----------------

__global__ void gat_node_k(const bf16* __restrict__ xl, const float* __restrict__ xr,
                           const float* __restrict__ We, const float* __restrict__ att,
                           const int* __restrict__ row_start, const int* __restrict__ src_sorted,
                           const float4* __restrict__ eattr_sorted,
                           float* __restrict__ out, int n) {
    int t = threadIdx.x;
    int c = t & 63;
    int node = blockIdx.x * 4 + (t >> 6);
    if (node >= n) return;
    float w0 = We[c], w1 = We[64 + c], w2 = We[128 + c], w3 = We[192 + c];
    float ratt = att[c] * 1.44269504f;   // fold log2(e): exp(a) == exp2(a*log2e)
    float xrd = xr[(size_t)node * 64 + c];
    int rs = row_start[node], re = row_start[node + 1];
    float srun = 0.f, acc = 0.f;
    int i = rs;
    for (; i + 2 <= re; i += 2) {
        int s0 = src_sorted[i], s1 = src_sorted[i + 1];
        float4 a0 = eattr_sorted[i], a1 = eattr_sorted[i + 1];
        float x0 = __bfloat162float(xl[(size_t)s0 * 64 + c]);
        float x1 = __bfloat162float(xl[(size_t)s1 * 64 + c]);
        float m0 = x0 + xrd, m1 = x1 + xrd;
        m0 = fmaf(a0.x, w0, m0); m1 = fmaf(a1.x, w0, m1);
        m0 = fmaf(a0.y, w1, m0); m1 = fmaf(a1.y, w1, m1);
        m0 = fmaf(a0.z, w2, m0); m1 = fmaf(a1.z, w2, m1);
        m0 = fmaf(a0.w, w3, m0); m1 = fmaf(a1.w, w3, m1);
        m0 = fmaxf(m0, 0.2f * m0);        // LeakyReLU(0.2)
        m1 = fmaxf(m1, 0.2f * m1);
        float v0 = m0 * ratt, v1 = m1 * ratt;
        v0 += __shfl_xor(v0, 1);  v1 += __shfl_xor(v1, 1);
        v0 += __shfl_xor(v0, 2);  v1 += __shfl_xor(v1, 2);
        v0 += __shfl_xor(v0, 4);  v1 += __shfl_xor(v1, 4);
        v0 += __shfl_xor(v0, 8);  v1 += __shfl_xor(v1, 8);
        float p0 = exp2f(v0), p1 = exp2f(v1);
        srun += p0 + p1;
        acc = fmaf(p0, x0, acc);
        acc = fmaf(p1, x1, acc);
    }
    if (i < re) {
        int s0 = src_sorted[i];
        float4 a0 = eattr_sorted[i];
        float x0 = __bfloat162float(xl[(size_t)s0 * 64 + c]);
        float m0 = x0 + xrd;
        m0 = fmaf(a0.x, w0, m0);
        m0 = fmaf(a0.y, w1, m0);
        m0 = fmaf(a0.z, w2, m0);
        m0 = fmaf(a0.w, w3, m0);
        m0 = fmaxf(m0, 0.2f * m0);
        float v0 = m0 * ratt;
        v0 += __shfl_xor(v0, 1);
        v0 += __shfl_xor(v0, 2);
        v0 += __shfl_xor(v0, 4);
        v0 += __shfl_xor(v0, 8);
        float p0 = exp2f(v0);
        srun += p0;
        acc = fmaf(p0, x0, acc);
    }
    out[(size_t)node * 64 + c] = acc / (srun + 1e-16f);
}

// ---------------- BN stats: 256 blocks x 256 threads, block-reduced ----------------

__global__ void bn_stats_k(const float* __restrict__ x, float* __restrict__ sums,
                           float* __restrict__ sqs, int n) {
    __shared__ float ls[256], lq[256];
    int t = threadIdx.x;
    int c = t & 63, sub = t >> 6;
    float s = 0.f, q = 0.f;
    for (int r = blockIdx.x * 4 + sub; r < n; r += gridDim.x * 4) {
        float v = x[(size_t)r * 64 + c];
        s += v;
        q = fmaf(v, v, q);
    }
    ls[t] = s; lq[t] = q;
    __syncthreads();
    if (t < 128) { ls[t] += ls[t + 128]; lq[t] += lq[t + 128]; }
    __syncthreads();
    if (t < 64) {
        atomicAdd(&sums[c], ls[t] + ls[t + 64]);
        atomicAdd(&sqs[c], lq[t] + lq[t + 64]);
    }
}

// ---------------- head fc 64->64, fused input BN+ELU ----------------

__global__ void lin1_k(const float* __restrict__ x, int n,
                       const float* __restrict__ sums, const float* __restrict__ sqs,
                       const float* __restrict__ g, const float* __restrict__ be,
                       const float* __restrict__ W, const float* __restrict__ b,
                       float* __restrict__ y, int ngroups) {
    __shared__ float sW[64 * 64];
    __shared__ float sx[4 * 64];
    int t = threadIdx.x;
    for (int i = t; i < 64 * 64; i += 256) sW[i] = W[i];
    int c = t & 63, nd = t >> 6;
    float inv_n = 1.f / n;
    float mu = sums[c] * inv_n;
    float var = sqs[c] * inv_n - mu * mu;
    float scc = rsqrtf(var + 1e-5f) * g[c];
    float sh = be[c] - mu * scc;
    float bc = b[c];
    for (int gs = blockIdx.x; gs < ngroups; gs += gridDim.x) {
        int node0 = gs * 4;
        __syncthreads();
        {
            int r = node0 + nd;
            float v = (r < n) ? x[(size_t)r * 64 + c] : 0.f;
            v = v * scc + sh;
            sx[t] = v > 0.f ? v : __expf(v) - 1.f;
        }
        __syncthreads();
        float a = bc;
        const float* sxr = sx + nd * 64;
#pragma unroll 8
        for (int k = 0; k < 64; ++k) a = fmaf(sxr[k], sW[k * 64 + c], a);
        int node = node0 + nd;
        if (node < n) y[(size_t)node * 64 + c] = a;
    }
}

// ---------------- final: fused BN+ELU + dot(64) + 5*tanh ----------------

__global__ void final_k(const float* __restrict__ z, int n,
                        const float* __restrict__ sums, const float* __restrict__ sqs,
                        const float* __restrict__ g, const float* __restrict__ be,
                        const float* __restrict__ W2, const float* __restrict__ b2,
                        float* __restrict__ out) {
    int t = blockIdx.x * blockDim.x + threadIdx.x;
    int node = t >> 6, c = t & 63;
    if (node >= n) return;
    float inv_n = 1.f / n;
    float mu = sums[c] * inv_n;
    float var = sqs[c] * inv_n - mu * mu;
    float scc = rsqrtf(var + 1e-5f) * g[c];
    float sh = be[c] - mu * scc;
    float v = z[(size_t)node * 64 + c] * scc + sh;
    v = v > 0.f ? v : __expf(v) - 1.f;
    v *= W2[c];
    v += __shfl_xor(v, 1);
    v += __shfl_xor(v, 2);
    v += __shfl_xor(v, 4);
    v += __shfl_xor(v, 8);
    v += __shfl_xor(v, 16);
    v += __shfl_xor(v, 32);
    if (c == 0) out[node] = 5.0f * tanhf(v + b2[0]);
}

// ---------------- launch ----------------

extern "C" void kernel_launch(void* const* d_in, const int* in_sizes, int n_in,
                              void* d_out, int out_size, void* d_ws, size_t ws_size,
                              hipStream_t stream) {
    const float* x0    = (const float*)d_in[0];
    const int*   eidx  = (const int*)d_in[1];
    const float* eattr = (const float*)d_in[2];

    const float* Wl[2]; const float* bl[2]; const float* Wr[2]; const float* br[2];
    const float* We[2]; const float* att[2]; const float* g[2]; const float* be[2];
    for (int l = 0; l < 2; ++l) {
        int base = 3 + l * 9;
        Wl[l]  = (const float*)d_in[base + 0];
        bl[l]  = (const float*)d_in[base + 1];
        Wr[l]  = (const float*)d_in[base + 2];
        br[l]  = (const float*)d_in[base + 3];
        We[l]  = (const float*)d_in[base + 4];
        att[l] = (const float*)d_in[base + 5];
        // base+6 = bias: per-channel constant, cancels exactly under BatchNorm
        g[l]   = (const float*)d_in[base + 7];
        be[l]  = (const float*)d_in[base + 8];
    }
    const float* W1 = (const float*)d_in[21];
    const float* b1 = (const float*)d_in[22];
    const float* gf = (const float*)d_in[23];
    const float* bf = (const float*)d_in[24];
    const float* W2 = (const float*)d_in[25];
    const float* b2 = (const float*)d_in[26];

    const int N = in_sizes[0] / 128;
    const int E = in_sizes[1] / 2;
    const int* src = eidx;
    const int* dst = eidx + E;

    // workspace layout (float units); eattr_sorted first for 16B alignment
    float* ws = (float*)d_ws;
    size_t o = 0;
    float4* eattr_sorted = (float4*)(ws + o); o += (size_t)E * 4;
    float*  xr   = ws + o; o += (size_t)N * HC;      // also reused as y (head fc out)
    float*  h0   = ws + o; o += (size_t)N * HC;
    float*  h1   = ws + o; o += (size_t)N * HC;
    bf16*   xl   = (bf16*)(ws + o); o += (size_t)N * HC / 2;
    int*    src_sorted = (int*)(ws + o); o += (size_t)E;
    int*    row_start  = (int*)(ws + o); o += (size_t)N + 1;
    int*    btot       = (int*)(ws + o); o += 256;
    int*    deg        = (int*)(ws + o); o += (size_t)N;
    int*    cursor     = (int*)(ws + o); o += (size_t)N;
    float*  stats = ws + o; o += 6 * HC;  // s0,q0,s1,q1,sf,qf
    float* s0 = stats,       *q0 = stats + 64;
    float* s1 = stats + 128, *q1 = stats + 192;
    float* sf = stats + 256, *qf = stats + 320;

    const int ngroups     = (N + 3) / 4;
    const int edge_blocks = (E + 255) / 256;
    const int nb          = (N + 255) / 256;

    hipMemsetAsync(deg, 0, (size_t)N * 4, stream);
    hipMemsetAsync(cursor, 0, (size_t)N * 4, stream);
    hipMemsetAsync(stats, 0, 6 * HC * 4, stream);

    // CSR build
    hist_k<<<edge_blocks, 256, 0, stream>>>(dst, deg, E);
    scan1_k<<<nb, 256, 0, stream>>>(deg, row_start, btot, N);
    scan2_k<<<1, 256, 0, stream>>>(btot, nb, row_start, N);
    scan3_k<<<nb, 256, 0, stream>>>(row_start, btot, N);
    scatter_k<<<edge_blocks, 256, 0, stream>>>(src, dst, eattr, row_start, cursor,
                                               src_sorted, eattr_sorted, E);

    // layer 0
    lin128_k<<<512, 256, 0, stream>>>(x0, N, Wl[0], bl[0], Wr[0], br[0], xl, xr, ngroups);
    gat_node_k<<<ngroups, 256, 0, stream>>>(xl, xr, We[0], att[0], row_start,
                                            src_sorted, eattr_sorted, h0, N);
    bn_stats_k<<<256, 256, 0, stream>>>(h0, s0, q0, N);

    // layer 1 (input BN+ELU fused into lin)
    lin64bn_k<<<1024, 256, 0, stream>>>(h0, N, s0, q0, g[0], be[0],
                                        Wl[1], bl[1], Wr[1], br[1], xl, xr, ngroups);
    gat_node_k<<<ngroups, 256, 0, stream>>>(xl, xr, We[1], att[1], row_start,
                                            src_sorted, eattr_sorted, h1, N);
    bn_stats_k<<<256, 256, 0, stream>>>(h1, s1, q1, N);

    // head: fc1 (BN+ELU fused on input) -> BN stats -> final (BN+ELU+dot+tanh)
    float* y = xr;  // xr dead after layer-1 gat
    lin1_k<<<1024, 256, 0, stream>>>(h1, N, s1, q1, g[1], be[1], W1, b1, y, ngroups);
    bn_stats_k<<<256, 256, 0, stream>>>(y, sf, qf, N);
    final_k<<<(int)(((size_t)N * 64 + 255) / 256), 256, 0, stream>>>(
        y, N, sf, qf, gf, bf, W2, b2, (float*)d_out);
}

// Round 4
// 554.896 us; speedup vs baseline: 3.2688x; 1.1710x over previous
//
#include <hip/hip_runtime.h>
#include <hip/hip_bf16.h>
#include <cmath>

#define HC 64
typedef __hip_bfloat16 bf16;

// ---------------- CSR build: hist + scan ----------------

__global__ void hist_k(const int* __restrict__ dst, int* __restrict__ deg, int E) {
    int e = blockIdx.x * blockDim.x + threadIdx.x;
    if (e < E) atomicAdd(&deg[dst[e]], 1);
}

__global__ void scan1_k(const int* __restrict__ deg, int* __restrict__ row_start,
                        int* __restrict__ btot, int n) {
    __shared__ int tmp[256];
    int t = threadIdx.x;
    int i = blockIdx.x * 256 + t;
    int v = (i < n) ? deg[i] : 0;
    tmp[t] = v;
    __syncthreads();
    for (int off = 1; off < 256; off <<= 1) {
        int a = (t >= off) ? tmp[t - off] : 0;
        __syncthreads();
        tmp[t] += a;
        __syncthreads();
    }
    if (i < n) row_start[i] = tmp[t] - v;
    if (t == 255) btot[blockIdx.x] = tmp[255];
}

__global__ void scan2_k(int* __restrict__ btot, int nb, int* __restrict__ row_start, int n) {
    __shared__ int tmp[256];
    int t = threadIdx.x;
    int v = (t < nb) ? btot[t] : 0;
    tmp[t] = v;
    __syncthreads();
    for (int off = 1; off < 256; off <<= 1) {
        int a = (t >= off) ? tmp[t - off] : 0;
        __syncthreads();
        tmp[t] += a;
        __syncthreads();
    }
    if (t < nb) btot[t] = tmp[t] - v;
    if (t == 255) row_start[n] = tmp[255];
}

__global__ void scan3_k(int* __restrict__ row_start, const int* __restrict__ btot, int n) {
    int i = blockIdx.x * blockDim.x + threadIdx.x;
    if (i < n) row_start[i] += btot[i >> 8];
}

// ---------------- bucketed sort (dst>>8 buckets for write locality) ----------------

__global__ void init_bcur_k(const int* __restrict__ row_start, int* __restrict__ bcur, int nbk) {
    int b = threadIdx.x;
    if (b < nbk) bcur[b] = row_start[b << 8];
}

__global__ __launch_bounds__(1024) void bucketA_k(
        const int* __restrict__ src, const int* __restrict__ dst,
        const float4* __restrict__ eattr, int* __restrict__ bcur,
        int2* __restrict__ tmp_sd, float4* __restrict__ tmp_ea, int E) {
    __shared__ int lcnt[256];
    __shared__ int lbase[256];
    int t = threadIdx.x;
    if (t < 256) lcnt[t] = 0;
    __syncthreads();
    int e = blockIdx.x * 1024 + t;
    int d = 0, b = 0, lpos = 0, s = 0;
    float4 ea = make_float4(0.f, 0.f, 0.f, 0.f);
    bool valid = (e < E);
    if (valid) {
        d = dst[e]; s = src[e]; ea = eattr[e];
        b = d >> 8;
        lpos = atomicAdd(&lcnt[b], 1);
    }
    __syncthreads();
    if (t < 256) {
        int c = lcnt[t];
        lbase[t] = c ? atomicAdd(&bcur[t], c) : 0;
    }
    __syncthreads();
    if (valid) {
        int pos = lbase[b] + lpos;
        tmp_sd[pos] = make_int2(s, d);
        tmp_ea[pos] = ea;
    }
}

__global__ void bucketB_k(const int2* __restrict__ tmp_sd, const float4* __restrict__ tmp_ea,
                          const int* __restrict__ row_start, int* __restrict__ cursor,
                          int* __restrict__ src_sorted, float4* __restrict__ eattr_sorted, int E) {
    int i = blockIdx.x * blockDim.x + threadIdx.x;
    if (i >= E) return;
    int2 sd = tmp_sd[i];
    int pos = row_start[sd.y] + atomicAdd(&cursor[sd.y], 1);
    src_sorted[pos] = sd.x;
    eattr_sorted[pos] = tmp_ea[i];
}

// ---------------- layer-0 linear: din=128, 16 nodes/block (4 per thread) ----------------

__global__ __launch_bounds__(256) void lin128_k(
        const float* __restrict__ x, int n,
        const float* __restrict__ Wl, const float* __restrict__ bl,
        const float* __restrict__ Wr, const float* __restrict__ br,
        bf16* __restrict__ xl, float* __restrict__ xr, int ngroups16) {
    __shared__ float2 sWl2[64 * 64];   // [k2][c] = {W[2k2][c], W[2k2+1][c]}
    __shared__ float2 sWr2[64 * 64];
    __shared__ float sx[16 * 128];
    int t = threadIdx.x;
    for (int i = t; i < 64 * 64; i += 256) {
        int k2 = i >> 6, c = i & 63;
        sWl2[i] = make_float2(Wl[(2 * k2) * 64 + c], Wl[(2 * k2 + 1) * 64 + c]);
        sWr2[i] = make_float2(Wr[(2 * k2) * 64 + c], Wr[(2 * k2 + 1) * 64 + c]);
    }
    int c = t & 63, w = t >> 6;
    float blc = bl[c], brc = br[c];
    for (int gidx = blockIdx.x; gidx < ngroups16; gidx += gridDim.x) {
        int node0 = gidx * 16;
        __syncthreads();
        for (int i = t; i < 16 * 128; i += 256) {
            int nd = i >> 7, k = i & 127;
            int r = node0 + nd;
            sx[i] = (r < n) ? x[(size_t)r * 128 + k] : 0.f;
        }
        __syncthreads();
        float al0 = blc, al1 = blc, al2 = blc, al3 = blc;
        float ar0 = brc, ar1 = brc, ar2 = brc, ar3 = brc;
        const float* sx0 = sx + w * 4 * 128;
#pragma unroll 8
        for (int k2 = 0; k2 < 64; ++k2) {
            float2 wl = sWl2[k2 * 64 + c], wr = sWr2[k2 * 64 + c];
            float2 xa = *(const float2*)&sx0[k2 * 2];
            float2 xb = *(const float2*)&sx0[128 + k2 * 2];
            float2 xc = *(const float2*)&sx0[256 + k2 * 2];
            float2 xd = *(const float2*)&sx0[384 + k2 * 2];
            al0 = fmaf(xa.x, wl.x, al0); al0 = fmaf(xa.y, wl.y, al0);
            ar0 = fmaf(xa.x, wr.x, ar0); ar0 = fmaf(xa.y, wr.y, ar0);
            al1 = fmaf(xb.x, wl.x, al1); al1 = fmaf(xb.y, wl.y, al1);
            ar1 = fmaf(xb.x, wr.x, ar1); ar1 = fmaf(xb.y, wr.y, ar1);
            al2 = fmaf(xc.x, wl.x, al2); al2 = fmaf(xc.y, wl.y, al2);
            ar2 = fmaf(xc.x, wr.x, ar2); ar2 = fmaf(xc.y, wr.y, ar2);
            al3 = fmaf(xd.x, wl.x, al3); al3 = fmaf(xd.y, wl.y, al3);
            ar3 = fmaf(xd.x, wr.x, ar3); ar3 = fmaf(xd.y, wr.y, ar3);
        }
        int nb_ = node0 + w * 4;
        if (nb_ + 0 < n) { xl[(size_t)(nb_ + 0) * 64 + c] = __float2bfloat16(al0); xr[(size_t)(nb_ + 0) * 64 + c] = ar0; }
        if (nb_ + 1 < n) { xl[(size_t)(nb_ + 1) * 64 + c] = __float2bfloat16(al1); xr[(size_t)(nb_ + 1) * 64 + c] = ar1; }
        if (nb_ + 2 < n) { xl[(size_t)(nb_ + 2) * 64 + c] = __float2bfloat16(al2); xr[(size_t)(nb_ + 2) * 64 + c] = ar2; }
        if (nb_ + 3 < n) { xl[(size_t)(nb_ + 3) * 64 + c] = __float2bfloat16(al3); xr[(size_t)(nb_ + 3) * 64 + c] = ar3; }
    }
}

// ---------------- layer-1 linear: din=64, fused input BN+ELU, 16 nodes/block ----------------

__global__ __launch_bounds__(256) void lin64bn_k(
        const float* __restrict__ x, int n,
        const float* __restrict__ sums, const float* __restrict__ sqs,
        const float* __restrict__ g, const float* __restrict__ be,
        const float* __restrict__ Wl, const float* __restrict__ bl,
        const float* __restrict__ Wr, const float* __restrict__ br,
        bf16* __restrict__ xl, float* __restrict__ xr, int ngroups16) {
    __shared__ float2 sWl2[32 * 64];
    __shared__ float2 sWr2[32 * 64];
    __shared__ float sx[16 * 64];
    __shared__ float ssc[64], ssh[64];
    int t = threadIdx.x;
    if (t < 64) {
        float inv_n = 1.f / n;
        float mu = sums[t] * inv_n;
        float var = sqs[t] * inv_n - mu * mu;
        float sc = rsqrtf(var + 1e-5f) * g[t];
        ssc[t] = sc; ssh[t] = be[t] - mu * sc;
    }
    for (int i = t; i < 32 * 64; i += 256) {
        int k2 = i >> 6, c = i & 63;
        sWl2[i] = make_float2(Wl[(2 * k2) * 64 + c], Wl[(2 * k2 + 1) * 64 + c]);
        sWr2[i] = make_float2(Wr[(2 * k2) * 64 + c], Wr[(2 * k2 + 1) * 64 + c]);
    }
    int c = t & 63, w = t >> 6;
    float blc = bl[c], brc = br[c];
    for (int gidx = blockIdx.x; gidx < ngroups16; gidx += gridDim.x) {
        int node0 = gidx * 16;
        __syncthreads();
        for (int i = t; i < 16 * 64; i += 256) {
            int nd = i >> 6, k = i & 63;
            int r = node0 + nd;
            float v = (r < n) ? x[(size_t)r * 64 + k] : 0.f;
            v = v * ssc[k] + ssh[k];
            sx[i] = v > 0.f ? v : __expf(v) - 1.f;
        }
        __syncthreads();
        float al0 = blc, al1 = blc, al2 = blc, al3 = blc;
        float ar0 = brc, ar1 = brc, ar2 = brc, ar3 = brc;
        const float* sx0 = sx + w * 4 * 64;
#pragma unroll 8
        for (int k2 = 0; k2 < 32; ++k2) {
            float2 wl = sWl2[k2 * 64 + c], wr = sWr2[k2 * 64 + c];
            float2 xa = *(const float2*)&sx0[k2 * 2];
            float2 xb = *(const float2*)&sx0[64 + k2 * 2];
            float2 xc = *(const float2*)&sx0[128 + k2 * 2];
            float2 xd = *(const float2*)&sx0[192 + k2 * 2];
            al0 = fmaf(xa.x, wl.x, al0); al0 = fmaf(xa.y, wl.y, al0);
            ar0 = fmaf(xa.x, wr.x, ar0); ar0 = fmaf(xa.y, wr.y, ar0);
            al1 = fmaf(xb.x, wl.x, al1); al1 = fmaf(xb.y, wl.y, al1);
            ar1 = fmaf(xb.x, wr.x, ar1); ar1 = fmaf(xb.y, wr.y, ar1);
            al2 = fmaf(xc.x, wl.x, al2); al2 = fmaf(xc.y, wl.y, al2);
            ar2 = fmaf(xc.x, wr.x, ar2); ar2 = fmaf(xc.y, wr.y, ar2);
            al3 = fmaf(xd.x, wl.x, al3); al3 = fmaf(xd.y, wl.y, al3);
            ar3 = fmaf(xd.x, wr.x, ar3); ar3 = fmaf(xd.y, wr.y, ar3);
        }
        int nb_ = node0 + w * 4;
        if (nb_ + 0 < n) { xl[(size_t)(nb_ + 0) * 64 + c] = __float2bfloat16(al0); xr[(size_t)(nb_ + 0) * 64 + c] = ar0; }
        if (nb_ + 1 < n) { xl[(size_t)(nb_ + 1) * 64 + c] = __float2bfloat16(al1); xr[(size_t)(nb_ + 1) * 64 + c] = ar1; }
        if (nb_ + 2 < n) { xl[(size_t)(nb_ + 2) * 64 + c] = __float2bfloat16(al2); xr[(size_t)(nb_ + 2) * 64 + c] = ar2; }
        if (nb_ + 3 < n) { xl[(size_t)(nb_ + 3) * 64 + c] = __float2bfloat16(al3); xr[(size_t)(nb_ + 3) * 64 + c] = ar3; }
    }
}

// ---------------- fused GAT: wave per destination node, unroll-4 ----------------

__global__ void gat_node_k(const bf16* __restrict__ xl, const float* __restrict__ xr,
                           const float* __restrict__ We, const float* __restrict__ att,
                           const int* __restrict__ row_start, const int* __restrict__ src_sorted,
                           const float4* __restrict__ eattr_sorted,
                           float* __restrict__ out, int n) {
    int t = threadIdx.x;
    int c = t & 63;
    int node = blockIdx.x * 4 + (t >> 6);
    if (node >= n) return;
    float w0 = We[c], w1 = We[64 + c], w2 = We[128 + c], w3 = We[192 + c];
    float ratt = att[c] * 1.44269504f;   // exp(a) = exp2(a*log2e)
    float xrd = xr[(size_t)node * 64 + c];
    int rs = row_start[node], re = row_start[node + 1];
    float srun = 0.f, acc = 0.f;
    int i = rs;
    for (; i + 4 <= re; i += 4) {
        int s0 = src_sorted[i], s1 = src_sorted[i + 1], s2 = src_sorted[i + 2], s3 = src_sorted[i + 3];
        float4 a0 = eattr_sorted[i], a1 = eattr_sorted[i + 1],
               a2 = eattr_sorted[i + 2], a3 = eattr_sorted[i + 3];
        float x0 = __bfloat162float(xl[((size_t)s0 << 6) + c]);
        float x1 = __bfloat162float(xl[((size_t)s1 << 6) + c]);
        float x2 = __bfloat162float(xl[((size_t)s2 << 6) + c]);
        float x3 = __bfloat162float(xl[((size_t)s3 << 6) + c]);
        float m0 = x0 + xrd, m1 = x1 + xrd, m2 = x2 + xrd, m3 = x3 + xrd;
        m0 = fmaf(a0.x, w0, m0); m1 = fmaf(a1.x, w0, m1); m2 = fmaf(a2.x, w0, m2); m3 = fmaf(a3.x, w0, m3);
        m0 = fmaf(a0.y, w1, m0); m1 = fmaf(a1.y, w1, m1); m2 = fmaf(a2.y, w1, m2); m3 = fmaf(a3.y, w1, m3);
        m0 = fmaf(a0.z, w2, m0); m1 = fmaf(a1.z, w2, m1); m2 = fmaf(a2.z, w2, m2); m3 = fmaf(a3.z, w2, m3);
        m0 = fmaf(a0.w, w3, m0); m1 = fmaf(a1.w, w3, m1); m2 = fmaf(a2.w, w3, m2); m3 = fmaf(a3.w, w3, m3);
        m0 = fmaxf(m0, 0.2f * m0); m1 = fmaxf(m1, 0.2f * m1);
        m2 = fmaxf(m2, 0.2f * m2); m3 = fmaxf(m3, 0.2f * m3);
        float v0 = m0 * ratt, v1 = m1 * ratt, v2 = m2 * ratt, v3 = m3 * ratt;
        v0 += __shfl_xor(v0, 1); v1 += __shfl_xor(v1, 1); v2 += __shfl_xor(v2, 1); v3 += __shfl_xor(v3, 1);
        v0 += __shfl_xor(v0, 2); v1 += __shfl_xor(v1, 2); v2 += __shfl_xor(v2, 2); v3 += __shfl_xor(v3, 2);
        v0 += __shfl_xor(v0, 4); v1 += __shfl_xor(v1, 4); v2 += __shfl_xor(v2, 4); v3 += __shfl_xor(v3, 4);
        v0 += __shfl_xor(v0, 8); v1 += __shfl_xor(v1, 8); v2 += __shfl_xor(v2, 8); v3 += __shfl_xor(v3, 8);
        float p0 = exp2f(v0), p1 = exp2f(v1), p2 = exp2f(v2), p3 = exp2f(v3);
        srun += (p0 + p1) + (p2 + p3);
        acc = fmaf(p0, x0, acc);
        acc = fmaf(p1, x1, acc);
        acc = fmaf(p2, x2, acc);
        acc = fmaf(p3, x3, acc);
    }
    for (; i < re; ++i) {
        int s0 = src_sorted[i];
        float4 a0 = eattr_sorted[i];
        float x0 = __bfloat162float(xl[((size_t)s0 << 6) + c]);
        float m0 = x0 + xrd;
        m0 = fmaf(a0.x, w0, m0);
        m0 = fmaf(a0.y, w1, m0);
        m0 = fmaf(a0.z, w2, m0);
        m0 = fmaf(a0.w, w3, m0);
        m0 = fmaxf(m0, 0.2f * m0);
        float v0 = m0 * ratt;
        v0 += __shfl_xor(v0, 1);
        v0 += __shfl_xor(v0, 2);
        v0 += __shfl_xor(v0, 4);
        v0 += __shfl_xor(v0, 8);
        float p0 = exp2f(v0);
        srun += p0;
        acc = fmaf(p0, x0, acc);
    }
    out[(size_t)node * 64 + c] = acc / (srun + 1e-16f);
}

// ---------------- BN stats ----------------

__global__ void bn_stats_k(const float* __restrict__ x, float* __restrict__ sums,
                           float* __restrict__ sqs, int n) {
    __shared__ float ls[256], lq[256];
    int t = threadIdx.x;
    int c = t & 63, sub = t >> 6;
    float s = 0.f, q = 0.f;
    for (int r = blockIdx.x * 4 + sub; r < n; r += gridDim.x * 4) {
        float v = x[(size_t)r * 64 + c];
        s += v;
        q = fmaf(v, v, q);
    }
    ls[t] = s; lq[t] = q;
    __syncthreads();
    if (t < 128) { ls[t] += ls[t + 128]; lq[t] += lq[t + 128]; }
    __syncthreads();
    if (t < 64) {
        atomicAdd(&sums[c], ls[t] + ls[t + 64]);
        atomicAdd(&sqs[c], lq[t] + lq[t + 64]);
    }
}

// ---------------- head fc 64->64 (fused input BN+ELU), 16 nodes/block ----------------

__global__ __launch_bounds__(256) void lin1_k(
        const float* __restrict__ x, int n,
        const float* __restrict__ sums, const float* __restrict__ sqs,
        const float* __restrict__ g, const float* __restrict__ be,
        const float* __restrict__ W, const float* __restrict__ b,
        float* __restrict__ y, int ngroups16) {
    __shared__ float2 sW2[32 * 64];
    __shared__ float sx[16 * 64];
    __shared__ float ssc[64], ssh[64];
    int t = threadIdx.x;
    if (t < 64) {
        float inv_n = 1.f / n;
        float mu = sums[t] * inv_n;
        float var = sqs[t] * inv_n - mu * mu;
        float sc = rsqrtf(var + 1e-5f) * g[t];
        ssc[t] = sc; ssh[t] = be[t] - mu * sc;
    }
    for (int i = t; i < 32 * 64; i += 256) {
        int k2 = i >> 6, c = i & 63;
        sW2[i] = make_float2(W[(2 * k2) * 64 + c], W[(2 * k2 + 1) * 64 + c]);
    }
    int c = t & 63, w = t >> 6;
    float bc = b[c];
    for (int gidx = blockIdx.x; gidx < ngroups16; gidx += gridDim.x) {
        int node0 = gidx * 16;
        __syncthreads();
        for (int i = t; i < 16 * 64; i += 256) {
            int nd = i >> 6, k = i & 63;
            int r = node0 + nd;
            float v = (r < n) ? x[(size_t)r * 64 + k] : 0.f;
            v = v * ssc[k] + ssh[k];
            sx[i] = v > 0.f ? v : __expf(v) - 1.f;
        }
        __syncthreads();
        float a0 = bc, a1 = bc, a2 = bc, a3 = bc;
        const float* sx0 = sx + w * 4 * 64;
#pragma unroll 8
        for (int k2 = 0; k2 < 32; ++k2) {
            float2 wv = sW2[k2 * 64 + c];
            float2 xa = *(const float2*)&sx0[k2 * 2];
            float2 xb = *(const float2*)&sx0[64 + k2 * 2];
            float2 xc = *(const float2*)&sx0[128 + k2 * 2];
            float2 xd = *(const float2*)&sx0[192 + k2 * 2];
            a0 = fmaf(xa.x, wv.x, a0); a0 = fmaf(xa.y, wv.y, a0);
            a1 = fmaf(xb.x, wv.x, a1); a1 = fmaf(xb.y, wv.y, a1);
            a2 = fmaf(xc.x, wv.x, a2); a2 = fmaf(xc.y, wv.y, a2);
            a3 = fmaf(xd.x, wv.x, a3); a3 = fmaf(xd.y, wv.y, a3);
        }
        int nb_ = node0 + w * 4;
        if (nb_ + 0 < n) y[(size_t)(nb_ + 0) * 64 + c] = a0;
        if (nb_ + 1 < n) y[(size_t)(nb_ + 1) * 64 + c] = a1;
        if (nb_ + 2 < n) y[(size_t)(nb_ + 2) * 64 + c] = a2;
        if (nb_ + 3 < n) y[(size_t)(nb_ + 3) * 64 + c] = a3;
    }
}

// ---------------- final: fused BN+ELU + dot(64) + 5*tanh ----------------

__global__ void final_k(const float* __restrict__ z, int n,
                        const float* __restrict__ sums, const float* __restrict__ sqs,
                        const float* __restrict__ g, const float* __restrict__ be,
                        const float* __restrict__ W2, const float* __restrict__ b2,
                        float* __restrict__ out) {
    int t = blockIdx.x * blockDim.x + threadIdx.x;
    int node = t >> 6, c = t & 63;
    if (node >= n) return;
    float inv_n = 1.f / n;
    float mu = sums[c] * inv_n;
    float var = sqs[c] * inv_n - mu * mu;
    float scc = rsqrtf(var + 1e-5f) * g[c];
    float sh = be[c] - mu * scc;
    float v = z[(size_t)node * 64 + c] * scc + sh;
    v = v > 0.f ? v : __expf(v) - 1.f;
    v *= W2[c];
    v += __shfl_xor(v, 1);
    v += __shfl_xor(v, 2);
    v += __shfl_xor(v, 4);
    v += __shfl_xor(v, 8);
    v += __shfl_xor(v, 16);
    v += __shfl_xor(v, 32);
    if (c == 0) out[node] = 5.0f * tanhf(v + b2[0]);
}

// ---------------- launch ----------------

extern "C" void kernel_launch(void* const* d_in, const int* in_sizes, int n_in,
                              void* d_out, int out_size, void* d_ws, size_t ws_size,
                              hipStream_t stream) {
    const float* x0    = (const float*)d_in[0];
    const int*   eidx  = (const int*)d_in[1];
    const float* eattr = (const float*)d_in[2];

    const float* Wl[2]; const float* bl[2]; const float* Wr[2]; const float* br[2];
    const float* We[2]; const float* att[2]; const float* g[2]; const float* be[2];
    for (int l = 0; l < 2; ++l) {
        int base = 3 + l * 9;
        Wl[l]  = (const float*)d_in[base + 0];
        bl[l]  = (const float*)d_in[base + 1];
        Wr[l]  = (const float*)d_in[base + 2];
        br[l]  = (const float*)d_in[base + 3];
        We[l]  = (const float*)d_in[base + 4];
        att[l] = (const float*)d_in[base + 5];
        // base+6 = bias: per-channel constant, cancels exactly under BatchNorm
        g[l]   = (const float*)d_in[base + 7];
        be[l]  = (const float*)d_in[base + 8];
    }
    const float* W1 = (const float*)d_in[21];
    const float* b1 = (const float*)d_in[22];
    const float* gf = (const float*)d_in[23];
    const float* bf = (const float*)d_in[24];
    const float* W2 = (const float*)d_in[25];
    const float* b2 = (const float*)d_in[26];

    const int N = in_sizes[0] / 128;
    const int E = in_sizes[1] / 2;
    const int* src = eidx;
    const int* dst = eidx + E;

    // workspace layout (float units)
    float* ws = (float*)d_ws;
    size_t o = 0;
    float4* eattr_sorted = (float4*)(ws + o); o += (size_t)E * 4;
    int*    src_sorted = (int*)(ws + o); o += (size_t)E;
    int*    row_start  = (int*)(ws + o); o += (size_t)N + 1;
    int*    btot       = (int*)(ws + o); o += 256;
    int*    deg        = (int*)(ws + o); o += (size_t)N;
    int*    cursor     = (int*)(ws + o); o += (size_t)N;
    int*    bcur       = (int*)(ws + o); o += 256;
    float*  stats = ws + o; o += 6 * HC;
    bf16*   xl   = (bf16*)(ws + o); o += (size_t)N * HC / 2;
    o = (o + 3) & ~(size_t)3;                 // 16B align for tmp_ea
    float*  big  = ws + o;                    // 3*N*64 floats == E*6 floats region
    float*  xr = big;
    float*  h0 = big + (size_t)N * HC;
    float*  h1 = big + (size_t)2 * N * HC;
    int2*   tmp_sd = (int2*)big;
    float4* tmp_ea = (float4*)(big + (size_t)E * 2);

    float* s0 = stats,        *q0 = stats + 64;
    float* s1 = stats + 128,  *q1 = stats + 192;
    float* sf = stats + 256,  *qf = stats + 320;

    const int ngroups4  = (N + 3) / 4;
    const int ngroups16 = (N + 15) / 16;
    const int edge_blocks = (E + 255) / 256;
    const int nb   = (N + 255) / 256;   // scan chunks
    const int nbk  = (N + 255) >> 8;    // sort buckets (dst>>8)

    hipMemsetAsync(deg, 0, (size_t)N * 4, stream);
    hipMemsetAsync(cursor, 0, (size_t)N * 4, stream);
    hipMemsetAsync(stats, 0, 6 * HC * 4, stream);

    // CSR build with locality-bucketed two-pass sort
    hist_k<<<edge_blocks, 256, 0, stream>>>(dst, deg, E);
    scan1_k<<<nb, 256, 0, stream>>>(deg, row_start, btot, N);
    scan2_k<<<1, 256, 0, stream>>>(btot, nb, row_start, N);
    scan3_k<<<nb, 256, 0, stream>>>(row_start, btot, N);
    init_bcur_k<<<1, 256, 0, stream>>>(row_start, bcur, nbk);
    bucketA_k<<<(E + 1023) / 1024, 1024, 0, stream>>>(src, dst, (const float4*)eattr,
                                                      bcur, tmp_sd, tmp_ea, E);
    bucketB_k<<<edge_blocks, 256, 0, stream>>>(tmp_sd, tmp_ea, row_start, cursor,
                                               src_sorted, eattr_sorted, E);

    // layer 0
    lin128_k<<<512, 256, 0, stream>>>(x0, N, Wl[0], bl[0], Wr[0], br[0], xl, xr, ngroups16);
    gat_node_k<<<ngroups4, 256, 0, stream>>>(xl, xr, We[0], att[0], row_start,
                                             src_sorted, eattr_sorted, h0, N);
    bn_stats_k<<<256, 256, 0, stream>>>(h0, s0, q0, N);

    // layer 1
    lin64bn_k<<<512, 256, 0, stream>>>(h0, N, s0, q0, g[0], be[0],
                                       Wl[1], bl[1], Wr[1], br[1], xl, xr, ngroups16);
    gat_node_k<<<ngroups4, 256, 0, stream>>>(xl, xr, We[1], att[1], row_start,
                                             src_sorted, eattr_sorted, h1, N);
    bn_stats_k<<<256, 256, 0, stream>>>(h1, s1, q1, N);

    // head
    float* y = xr;  // xr dead after layer-1 gat
    lin1_k<<<512, 256, 0, stream>>>(h1, N, s1, q1, g[1], be[1], W1, b1, y, ngroups16);
    bn_stats_k<<<256, 256, 0, stream>>>(y, sf, qf, N);
    final_k<<<(int)(((size_t)N * 64 + 255) / 256), 256, 0, stream>>>(
        y, N, sf, qf, gf, bf, W2, b2, (float*)d_out);
}